// Round 7
// baseline (640.638 us; speedup 1.0000x reference)
//
#include <hip/hip_runtime.h>
#include <math.h>

#define FDIM 64
#define RDIM 16
#define LN2F 0.69314718055994530942f
#define LTS 68       // LDS tile row stride (floats)
#define NBINR 14336  // bins per range-pass (56KB LDS), 7 ranges cover 100K atoms
#define NCHUNK 64    // pair chunks (Cmat[chunk][bin] aliases workspace region)

typedef __bf16 bf8_t __attribute__((ext_vector_type(8)));
typedef float  f4_t  __attribute__((ext_vector_type(4)));
typedef _Float16 h2_t __attribute__((ext_vector_type(2)));

// Numerically stable softplus (fast intrinsics)
__device__ __forceinline__ float sp(float x) {
    return fmaxf(x, 0.0f) + __logf(1.0f + __expf(-fabsf(x)));
}

// fp16 dot2 with f32 accumulate (V_DOT2_F32_F16); fallback if builtin missing
__device__ __forceinline__ float fdot2f(h2_t a, h2_t b, float c) {
#if __has_builtin(__builtin_amdgcn_fdot2)
    return __builtin_amdgcn_fdot2(a, b, c, false);
#else
    return c + (float)a[0] * (float)b[0] + (float)a[1] * (float)b[1];
#endif
}

// convert one f32 row (16) to fp16 and store 32B
__device__ __forceinline__ void cvt_store16(_Float16* dst, float4 A, float4 B,
                                            float4 C4, float4 D)
{
    h2_t hv[8];
    hv[0] = h2_t{(_Float16)A.x,  (_Float16)A.y};
    hv[1] = h2_t{(_Float16)A.z,  (_Float16)A.w};
    hv[2] = h2_t{(_Float16)B.x,  (_Float16)B.y};
    hv[3] = h2_t{(_Float16)B.z,  (_Float16)B.w};
    hv[4] = h2_t{(_Float16)C4.x, (_Float16)C4.y};
    hv[5] = h2_t{(_Float16)C4.z, (_Float16)C4.w};
    hv[6] = h2_t{(_Float16)D.x,  (_Float16)D.y};
    hv[7] = h2_t{(_Float16)D.z,  (_Float16)D.w};
    *(uint4*)dst       = *(const uint4*)&hv[0];
    *(uint4*)(dst + 8) = *(const uint4*)&hv[4];
}

// ---------------- weight prep: fp32 [k][c] -> bf16 B-fragment layout ----------
__global__ __launch_bounds__(256) void k_prep(
    const float* s0, const float* s1, const float* s2, const float* s3,
    const float* s4, const float* s5, const float* s6, const float* s7,
    const float* s8, __bf16* __restrict__ dst)
{
    const float* srcs[9] = {s0, s1, s2, s3, s4, s5, s6, s7, s8};
    const float* W = srcs[blockIdx.x];
    __bf16* d = dst + (size_t)blockIdx.x * 4096;
    for (int slot = threadIdx.x; slot < 512; slot += 256) {
        int f = slot >> 6, l = slot & 63;
        int kt = f >> 2, nt = f & 3;
        int row0 = kt * 32 + (l >> 4) * 8;
        int col = nt * 16 + (l & 15);
#pragma unroll
        for (int j = 0; j < 8; ++j)
            d[slot * 8 + j] = (__bf16)W[(row0 + j) * FDIM + col];
    }
}

// ---------------- hist: LDS-private per-(chunk,range) histograms --------------
__global__ __launch_bounds__(256) void k_hist2(
    const int* __restrict__ idx_i, int* __restrict__ Cmat,
    int P, int N, int nRange)
{
    __shared__ int h[NBINR];
    const int chunk = blockIdx.x / nRange;
    const int range = blockIdx.x % nRange;
    const int lo = range * NBINR;
    const int nb = min(NBINR, N - lo);
    for (int u = threadIdx.x; u < NBINR; u += 256) h[u] = 0;
    __syncthreads();

    const int chunkSz = (P + NCHUNK - 1) / NCHUNK;
    const int cs = chunk * chunkSz;
    const int ce = min(P, cs + chunkSz);
    int p = cs + threadIdx.x;
    for (; p + 768 < ce; p += 1024) {
        int i0 = idx_i[p];
        int i1 = idx_i[p + 256];
        int i2 = idx_i[p + 512];
        int i3 = idx_i[p + 768];
        unsigned u0 = (unsigned)(i0 - lo);
        unsigned u1 = (unsigned)(i1 - lo);
        unsigned u2 = (unsigned)(i2 - lo);
        unsigned u3 = (unsigned)(i3 - lo);
        if (u0 < (unsigned)nb) atomicAdd(&h[u0], 1);
        if (u1 < (unsigned)nb) atomicAdd(&h[u1], 1);
        if (u2 < (unsigned)nb) atomicAdd(&h[u2], 1);
        if (u3 < (unsigned)nb) atomicAdd(&h[u3], 1);
    }
    for (; p < ce; p += 256) {
        unsigned u = (unsigned)(idx_i[p] - lo);
        if (u < (unsigned)nb) atomicAdd(&h[u], 1);
    }
    __syncthreads();
    for (int u = threadIdx.x; u < nb; u += 256)
        Cmat[(size_t)chunk * N + lo + u] = h[u];
}

// ---------------- scanR: Cmat -> per-chunk exclusive bases (in place) + totals
__global__ __launch_bounds__(256) void k_scanR(
    int* __restrict__ Cmat, int* __restrict__ tot, int N)
{
    const int bA = blockIdx.x * 512 + threadIdx.x;
    const int bB = bA + 256;
    const bool okA = bA < N, okB = bB < N;
    int runA = 0, runB = 0;
    for (int c = 0; c < NCHUNK; ++c) {
        const size_t base = (size_t)c * N;
        if (okA) { int val = Cmat[base + bA]; Cmat[base + bA] = runA; runA += val; }
        if (okB) { int val = Cmat[base + bB]; Cmat[base + bB] = runB; runB += val; }
    }
    if (okA) tot[bA] = runA;
    if (okB) tot[bB] = runB;
}

// ---------------- tile in: coalesced global -> wave-private LDS ----------------
__device__ __forceinline__ void tile_in(float* T, const float* __restrict__ src,
                                        int a0, int rows, int lane)
{
#pragma unroll 4
    for (int i = 0; i < 16; ++i) {
        int r = i * 4 + (lane >> 4);
        int col = (lane & 15) * 4;
        float4 val = make_float4(0.f, 0.f, 0.f, 0.f);
        if (r < rows) val = *(const float4*)&src[(size_t)(a0 + r) * FDIM + col];
        *(float4*)&T[r * LTS + col] = val;
    }
}

// build A-fragments (bf16) for a 64x64 LDS tile: aF[mt][kt]
__device__ __forceinline__ void build_a(const float* T, int lane, bool actLn2,
                                        bf8_t (&aF)[4][2])
{
    const int l15 = lane & 15, quad = lane >> 4;
#pragma unroll
    for (int mt = 0; mt < 4; ++mt) {
#pragma unroll
        for (int kt = 0; kt < 2; ++kt) {
            const float* rp = &T[(mt * 16 + l15) * LTS + kt * 32 + quad * 8];
            float4 u0 = *(const float4*)rp;
            float4 u1 = *(const float4*)(rp + 4);
            float e[8] = {u0.x, u0.y, u0.z, u0.w, u1.x, u1.y, u1.z, u1.w};
            bf8_t f;
#pragma unroll
            for (int j = 0; j < 8; ++j) {
                float t = actLn2 ? (sp(e[j]) - LN2F) : e[j];
                f[j] = (__bf16)t;
            }
            aF[mt][kt] = f;
        }
    }
}

// ---------------- k_atoms: x=sp(emb)-ln2; v=sp(x@Wi+bi); y16=sp(x@Wj+bj) ------
__global__ __launch_bounds__(256) void k_atoms(
    const float* __restrict__ emb, const __bf16* __restrict__ wf,
    const float* __restrict__ bi, const float* __restrict__ bj,
    float* __restrict__ v, _Float16* __restrict__ y16, int N)
{
    __shared__ float tile[4][64 * LTS];
    const int lane = threadIdx.x & 63;
    const int wv = threadIdx.x >> 6;
    float* T = tile[wv];
    const int l15 = lane & 15, quad = lane >> 4;

    const bf8_t* wiF = (const bf8_t*)wf;            // matrix 0
    const bf8_t* wjF = (const bf8_t*)(wf + 4096);   // matrix 1
    bf8_t wi[2][4], wj[2][4];
#pragma unroll
    for (int kt = 0; kt < 2; ++kt)
#pragma unroll
        for (int nt = 0; nt < 4; ++nt) {
            wi[kt][nt] = wiF[(kt * 4 + nt) * 64 + lane];
            wj[kt][nt] = wjF[(kt * 4 + nt) * 64 + lane];
        }
    float biv[4], bjv[4];
#pragma unroll
    for (int nt = 0; nt < 4; ++nt) {
        biv[nt] = bi[nt * 16 + l15];
        bjv[nt] = bj[nt * 16 + l15];
    }

    const int nTiles = (N + 63) >> 6;
    for (int t = blockIdx.x * 4 + wv; t < nTiles; t += gridDim.x * 4) {
        const int a0 = t << 6;
        const int rows = min(64, N - a0);
        tile_in(T, emb, a0, rows, lane);
        bf8_t aF[4][2];
        build_a(T, lane, true, aF);
#pragma unroll
        for (int mt = 0; mt < 4; ++mt)
#pragma unroll
            for (int nt = 0; nt < 4; ++nt) {
                f4_t acc = {biv[nt], biv[nt], biv[nt], biv[nt]};
                acc = __builtin_amdgcn_mfma_f32_16x16x32_bf16(aF[mt][0], wi[0][nt], acc, 0, 0, 0);
                acc = __builtin_amdgcn_mfma_f32_16x16x32_bf16(aF[mt][1], wi[1][nt], acc, 0, 0, 0);
#pragma unroll
                for (int reg = 0; reg < 4; ++reg) {
                    int r = mt * 16 + quad * 4 + reg;
                    if (r < rows) v[(size_t)(a0 + r) * FDIM + nt * 16 + l15] = sp(acc[reg]);
                }
            }
#pragma unroll
        for (int mt = 0; mt < 4; ++mt)
#pragma unroll
            for (int nt = 0; nt < 4; ++nt) {
                f4_t acc = {bjv[nt], bjv[nt], bjv[nt], bjv[nt]};
                acc = __builtin_amdgcn_mfma_f32_16x16x32_bf16(aF[mt][0], wj[0][nt], acc, 0, 0, 0);
                acc = __builtin_amdgcn_mfma_f32_16x16x32_bf16(aF[mt][1], wj[1][nt], acc, 0, 0, 0);
#pragma unroll
                for (int reg = 0; reg < 4; ++reg) {
                    int r = mt * 16 + quad * 4 + reg;
                    if (r < rows)
                        y16[(size_t)(a0 + r) * FDIM + nt * 16 + l15] = (_Float16)sp(acc[reg]);
                }
            }
    }
}

// ---------------- k_post: fused 3 residual blocks + final projection (MFMA) ---
__global__ __launch_bounds__(256) void k_post(
    const __bf16* __restrict__ wf,
    const float* __restrict__ rb1, const float* __restrict__ rb2,
    const float* __restrict__ bv,
    float* __restrict__ v, int N)
{
    __shared__ float tile[4][64 * LTS];
    const int lane = threadIdx.x & 63;
    const int wv = threadIdx.x >> 6;
    float* T = tile[wv];
    const int l15 = lane & 15, quad = lane >> 4;

    float b1v[3][4], b2v[3][4], bvv[4];
#pragma unroll
    for (int l = 0; l < 3; ++l)
#pragma unroll
        for (int nt = 0; nt < 4; ++nt) {
            b1v[l][nt] = rb1[l * FDIM + nt * 16 + l15];
            b2v[l][nt] = rb2[l * FDIM + nt * 16 + l15];
        }
#pragma unroll
    for (int nt = 0; nt < 4; ++nt) bvv[nt] = bv[nt * 16 + l15];

    const int nTiles = (N + 63) >> 6;
    for (int t = blockIdx.x * 4 + wv; t < nTiles; t += gridDim.x * 4) {
        const int a0 = t << 6;
        const int rows = min(64, N - a0);
        tile_in(T, v, a0, rows, lane);
        float vC[16][4];
#pragma unroll
        for (int mt = 0; mt < 4; ++mt)
#pragma unroll
            for (int nt = 0; nt < 4; ++nt)
#pragma unroll
                for (int reg = 0; reg < 4; ++reg)
                    vC[mt * 4 + nt][reg] =
                        T[(mt * 16 + quad * 4 + reg) * LTS + nt * 16 + l15];

        for (int l = 0; l < 3; ++l) {
            const bf8_t* w1f = (const bf8_t*)(wf + (size_t)(2 * l) * 4096);
            const bf8_t* w2f = (const bf8_t*)(wf + (size_t)(2 * l + 1) * 4096);
            bf8_t aF[4][2];
            build_a(T, lane, false, aF);
#pragma unroll
            for (int mt = 0; mt < 4; ++mt)
#pragma unroll
                for (int nt = 0; nt < 4; ++nt) {
                    f4_t acc = {b1v[l][nt], b1v[l][nt], b1v[l][nt], b1v[l][nt]};
                    acc = __builtin_amdgcn_mfma_f32_16x16x32_bf16(aF[mt][0], w1f[(0 * 4 + nt) * 64 + lane], acc, 0, 0, 0);
                    acc = __builtin_amdgcn_mfma_f32_16x16x32_bf16(aF[mt][1], w1f[(1 * 4 + nt) * 64 + lane], acc, 0, 0, 0);
#pragma unroll
                    for (int reg = 0; reg < 4; ++reg)
                        T[(mt * 16 + quad * 4 + reg) * LTS + nt * 16 + l15] = sp(acc[reg]);
                }
            bf8_t hF[4][2];
            build_a(T, lane, false, hF);
#pragma unroll
            for (int mt = 0; mt < 4; ++mt)
#pragma unroll
                for (int nt = 0; nt < 4; ++nt) {
                    f4_t acc = {b2v[l][nt], b2v[l][nt], b2v[l][nt], b2v[l][nt]};
                    acc = __builtin_amdgcn_mfma_f32_16x16x32_bf16(hF[mt][0], w2f[(0 * 4 + nt) * 64 + lane], acc, 0, 0, 0);
                    acc = __builtin_amdgcn_mfma_f32_16x16x32_bf16(hF[mt][1], w2f[(1 * 4 + nt) * 64 + lane], acc, 0, 0, 0);
#pragma unroll
                    for (int reg = 0; reg < 4; ++reg)
                        vC[mt * 4 + nt][reg] += acc[reg];
                }
            if (l < 2) {
#pragma unroll
                for (int mt = 0; mt < 4; ++mt)
#pragma unroll
                    for (int nt = 0; nt < 4; ++nt)
#pragma unroll
                        for (int reg = 0; reg < 4; ++reg)
                            T[(mt * 16 + quad * 4 + reg) * LTS + nt * 16 + l15] =
                                vC[mt * 4 + nt][reg];
            }
        }
#pragma unroll
        for (int mt = 0; mt < 4; ++mt)
#pragma unroll
            for (int nt = 0; nt < 4; ++nt)
#pragma unroll
                for (int reg = 0; reg < 4; ++reg)
                    T[(mt * 16 + quad * 4 + reg) * LTS + nt * 16 + l15] =
                        sp(vC[mt * 4 + nt][reg]);
        bf8_t fF[4][2];
        build_a(T, lane, false, fF);
        const bf8_t* wvf = (const bf8_t*)(wf + (size_t)6 * 4096);
#pragma unroll
        for (int mt = 0; mt < 4; ++mt)
#pragma unroll
            for (int nt = 0; nt < 4; ++nt) {
                f4_t acc = {bvv[nt], bvv[nt], bvv[nt], bvv[nt]};
                acc = __builtin_amdgcn_mfma_f32_16x16x32_bf16(fF[mt][0], wvf[(0 * 4 + nt) * 64 + lane], acc, 0, 0, 0);
                acc = __builtin_amdgcn_mfma_f32_16x16x32_bf16(fF[mt][1], wvf[(1 * 4 + nt) * 64 + lane], acc, 0, 0, 0);
#pragma unroll
                for (int reg = 0; reg < 4; ++reg) {
                    int r = mt * 16 + quad * 4 + reg;
                    if (r < rows) v[(size_t)(a0 + r) * FDIM + nt * 16 + l15] = acc[reg];
                }
            }
    }
}

// ---------------- global scan over per-bin totals -----------------------------
__global__ __launch_bounds__(256) void k_scan_a(
    const int* __restrict__ cnt, int* __restrict__ part, int N)
{
    __shared__ int red[256];
    int b = blockIdx.x, t = threadIdx.x;
    int base = b * 1024 + t * 4;
    int s = 0;
#pragma unroll
    for (int i = 0; i < 4; ++i) { int a = base + i; if (a < N) s += cnt[a]; }
    red[t] = s; __syncthreads();
    for (int off = 128; off > 0; off >>= 1) {
        if (t < off) red[t] += red[t + off];
        __syncthreads();
    }
    if (t == 0) part[b] = red[0];
}

__global__ __launch_bounds__(256) void k_scan_b(int* __restrict__ part, int nPart)
{
    __shared__ int lds[256];
    int t = threadIdx.x;
    int base = t * 4;
    int v[4]; int s = 0;
#pragma unroll
    for (int i = 0; i < 4; ++i) { v[i] = (base + i < nPart) ? part[base + i] : 0; s += v[i]; }
    lds[t] = s; __syncthreads();
    int run = s;
    for (int off = 1; off < 256; off <<= 1) {
        int x = (t >= off) ? lds[t - off] : 0;
        __syncthreads();
        lds[t] += x;
        __syncthreads();
    }
    int excl = lds[t] - run;
#pragma unroll
    for (int i = 0; i < 4; ++i) { if (base + i < nPart) { part[base + i] = excl; excl += v[i]; } }
}

__global__ __launch_bounds__(256) void k_scan_c(
    const int* __restrict__ cnt, const int* __restrict__ part,
    int* __restrict__ start, int N, int P)
{
    __shared__ int lds[256];
    int b = blockIdx.x, t = threadIdx.x;
    int base = b * 1024 + t * 4;
    int v[4]; int s = 0;
#pragma unroll
    for (int i = 0; i < 4; ++i) { int a = base + i; v[i] = (a < N) ? cnt[a] : 0; s += v[i]; }
    lds[t] = s; __syncthreads();
    int run = s;
    for (int off = 1; off < 256; off <<= 1) {
        int x = (t >= off) ? lds[t - off] : 0;
        __syncthreads();
        lds[t] += x;
        __syncthreads();
    }
    int pre = part[b] + (lds[t] - run);
#pragma unroll
    for (int i = 0; i < 4; ++i) {
        int a = base + i;
        if (a < N) { start[a] = pre; pre += v[i]; }
    }
    if (b == 0 && t == 0) start[N] = P;
}

// ---------------- scatter: LDS cursors; writes sortedJ[pos]=j, invPos[p]=pos --
// invPos write is coalesced (p is the loop variable); sortedJ is 4B scattered.
__global__ __launch_bounds__(256) void k_scatter2(
    const int* __restrict__ pidx, const int* __restrict__ Cmat,
    const int* __restrict__ start, int* __restrict__ sortedJ,
    int* __restrict__ invPos, int P, int N, int nRange)
{
    __shared__ int cur[NBINR];
    const int chunk = blockIdx.x / nRange;
    const int range = blockIdx.x % nRange;
    const int lo = range * NBINR;
    const int nb = min(NBINR, N - lo);
    for (int u = threadIdx.x; u < nb; u += 256)
        cur[u] = start[lo + u] + Cmat[(size_t)chunk * N + lo + u];
    __syncthreads();

    const int chunkSz = (P + NCHUNK - 1) / NCHUNK;
    const int cs = chunk * chunkSz;
    const int ce = min(P, cs + chunkSz);
    int p = cs + threadIdx.x;
    for (; p + 768 < ce; p += 1024) {
        int i0 = pidx[p];
        int i1 = pidx[p + 256];
        int i2 = pidx[p + 512];
        int i3 = pidx[p + 768];
        int j0 = pidx[P + p];
        int j1 = pidx[P + p + 256];
        int j2 = pidx[P + p + 512];
        int j3 = pidx[P + p + 768];
        unsigned u0 = (unsigned)(i0 - lo);
        unsigned u1 = (unsigned)(i1 - lo);
        unsigned u2 = (unsigned)(i2 - lo);
        unsigned u3 = (unsigned)(i3 - lo);
        if (u0 < (unsigned)nb) { int pos = atomicAdd(&cur[u0], 1); sortedJ[pos] = j0; invPos[p] = pos; }
        if (u1 < (unsigned)nb) { int pos = atomicAdd(&cur[u1], 1); sortedJ[pos] = j1; invPos[p + 256] = pos; }
        if (u2 < (unsigned)nb) { int pos = atomicAdd(&cur[u2], 1); sortedJ[pos] = j2; invPos[p + 512] = pos; }
        if (u3 < (unsigned)nb) { int pos = atomicAdd(&cur[u3], 1); sortedJ[pos] = j3; invPos[p + 768] = pos; }
    }
    for (; p < ce; p += 256) {
        int i = pidx[p];
        unsigned u = (unsigned)(i - lo);
        if (u < (unsigned)nb) {
            int j = pidx[P + p];
            int pos = atomicAdd(&cur[u], 1);
            sortedJ[pos] = j;
            invPos[p] = pos;
        }
    }
}

// ---------------- gatherF2: SEQUENTIAL f_ij read, scattered fp16 row write ----
// Random access moved to the write side (fire-and-forget, L2-absorbed).
__global__ __launch_bounds__(256) void k_gatherF2(
    const float* __restrict__ f_ij, const int* __restrict__ invPos,
    _Float16* __restrict__ sortedF, int P)
{
    int t = blockIdx.x * blockDim.x + threadIdx.x;
    int n = gridDim.x * blockDim.x;
    int p = t;
    for (; p + 3 * n < P; p += 4 * n) {
        int q0 = invPos[p];
        int q1 = invPos[p + n];
        int q2 = invPos[p + 2 * n];
        int q3 = invPos[p + 3 * n];
        const float4* f0 = (const float4*)(f_ij + (size_t)p * RDIM);
        const float4* f1 = (const float4*)(f_ij + (size_t)(p + n) * RDIM);
        const float4* f2 = (const float4*)(f_ij + (size_t)(p + 2 * n) * RDIM);
        const float4* f3 = (const float4*)(f_ij + (size_t)(p + 3 * n) * RDIM);
        float4 a0 = f0[0], b0 = f0[1], c0 = f0[2], d0 = f0[3];
        float4 a1 = f1[0], b1 = f1[1], c1 = f1[2], d1 = f1[3];
        float4 a2 = f2[0], b2 = f2[1], c2 = f2[2], d2 = f2[3];
        float4 a3 = f3[0], b3 = f3[1], c3 = f3[2], d3 = f3[3];
        cvt_store16(sortedF + (size_t)q0 * 16, a0, b0, c0, d0);
        cvt_store16(sortedF + (size_t)q1 * 16, a1, b1, c1, d1);
        cvt_store16(sortedF + (size_t)q2 * 16, a2, b2, c2, d2);
        cvt_store16(sortedF + (size_t)q3 * 16, a3, b3, c3, d3);
    }
    for (; p < P; p += n) {
        int q = invPos[p];
        const float4* fp = (const float4*)(f_ij + (size_t)p * RDIM);
        float4 A = fp[0], B = fp[1], C4 = fp[2], D = fp[3];
        cvt_store16(sortedF + (size_t)q * 16, A, B, C4, D);
    }
}

// ---------------- k_seg -------------------------------------------------------
// out[a,c] = sum_p dot16(G[c,:], f_p) * y[j_p, c]
// sortedF sequential fp16 + v_dot2; y16 rows are 128B (one line per gather).
__global__ __launch_bounds__(256) void k_seg(
    const int* __restrict__ sortedJ, const _Float16* __restrict__ sortedF,
    const int* __restrict__ start, const float* __restrict__ G,
    const _Float16* __restrict__ y16, float* __restrict__ v, int N)
{
    const int c = threadIdx.x & 63;
    const int w = __builtin_amdgcn_readfirstlane((blockIdx.x << 2) | (threadIdx.x >> 6));
    const int nw = gridDim.x << 2;

    // G row for this lane, packed to fp16 pairs (8 dot2 operands)
    h2_t g2[8];
    {
        const float4* gp = (const float4*)(G + c * RDIM);
        float4 g0 = gp[0], g1 = gp[1], g2v = gp[2], g3 = gp[3];
        g2[0] = h2_t{(_Float16)g0.x, (_Float16)g0.y};
        g2[1] = h2_t{(_Float16)g0.z, (_Float16)g0.w};
        g2[2] = h2_t{(_Float16)g1.x, (_Float16)g1.y};
        g2[3] = h2_t{(_Float16)g1.z, (_Float16)g1.w};
        g2[4] = h2_t{(_Float16)g2v.x, (_Float16)g2v.y};
        g2[5] = h2_t{(_Float16)g2v.z, (_Float16)g2v.w};
        g2[6] = h2_t{(_Float16)g3.x, (_Float16)g3.y};
        g2[7] = h2_t{(_Float16)g3.z, (_Float16)g3.w};
    }

    for (int a = w; a < N; a += nw) {
        const int s = __builtin_amdgcn_readfirstlane(start[a]);
        const int e = __builtin_amdgcn_readfirstlane(start[a + 1]);
        float vold = v[(size_t)a * FDIM + c];   // hoist RMW read over the pair loop
        float acc0 = 0.f, acc1 = 0.f, acc2 = 0.f, acc3 = 0.f;

        for (int base = s; base < e; base += 64) {
            const int nn = (e - base < 64) ? (e - base) : 64;
            const int li = (c < nn) ? c : (nn - 1);
            const int jkv = sortedJ[base + li];   // lane l holds j of pair base+l

            int k = 0;
            for (; k + 8 <= nn; k += 8) {
                int jj[8];
#pragma unroll
                for (int u = 0; u < 8; ++u)
                    jj[u] = __builtin_amdgcn_readlane(jkv, k + u);
                float yv[8];
#pragma unroll
                for (int u = 0; u < 8; ++u)
                    yv[u] = (float)y16[(size_t)jj[u] * FDIM + c];
                const h2_t* f2 = (const h2_t*)(sortedF + (size_t)(base + k) * 16);
#pragma unroll
                for (int u = 0; u < 8; ++u) {
                    float d = 0.f;
#pragma unroll
                    for (int r = 0; r < 8; ++r)
                        d = fdot2f(f2[u * 8 + r], g2[r], d);
                    if ((u & 3) == 0) acc0 = fmaf(d, yv[u], acc0);
                    else if ((u & 3) == 1) acc1 = fmaf(d, yv[u], acc1);
                    else if ((u & 3) == 2) acc2 = fmaf(d, yv[u], acc2);
                    else acc3 = fmaf(d, yv[u], acc3);
                }
            }
            for (; k < nn; ++k) {
                const int j0 = __builtin_amdgcn_readlane(jkv, k);
                float y0 = (float)y16[(size_t)j0 * FDIM + c];
                const h2_t* f2 = (const h2_t*)(sortedF + (size_t)(base + k) * 16);
                float d = 0.f;
#pragma unroll
                for (int r = 0; r < 8; ++r)
                    d = fdot2f(f2[r], g2[r], d);
                acc0 = fmaf(d, y0, acc0);
            }
        }

        v[(size_t)a * FDIM + c] = vold + (acc0 + acc1) + (acc2 + acc3);
    }
}

extern "C" void kernel_launch(void* const* d_in, const int* in_sizes, int n_in,
                              void* d_out, int out_size, void* d_ws, size_t ws_size,
                              hipStream_t stream)
{
    const int*   pidx = (const int*)d_in[0];    // [2, P]
    const float* f_ij = (const float*)d_in[1];  // [P, 1, R]
    const float* emb  = (const float*)d_in[3];  // [N, F]
    const float* G    = (const float*)d_in[4];  // [F, R]
    const float* Wi   = (const float*)d_in[5];
    const float* bi   = (const float*)d_in[6];
    const float* Wj   = (const float*)d_in[7];
    const float* bj   = (const float*)d_in[8];
    const float* rW1  = (const float*)d_in[9];
    const float* rb1  = (const float*)d_in[10];
    const float* rW2  = (const float*)d_in[11];
    const float* rb2  = (const float*)d_in[12];
    const float* Wv   = (const float*)d_in[13];
    const float* bv   = (const float*)d_in[14];

    const int P = in_sizes[0] / 2;
    const int N = in_sizes[3] / FDIM;

    float* v = (float*)d_out;

    // workspace layout. Cmat (int[NCHUNK*N] = 25.6MB) shares its region with
    // y16 (N*64 fp16 = 12.8MB): Cmat is dead after k_scatter2; k_atoms writes
    // y16 afterwards.
    char* ws = (char*)d_ws;
    size_t off = 0;
    _Float16* y16  = (_Float16*)(ws + off);
    int*    Cmat   = (int*)(ws + off);    off += (size_t)N * FDIM * 4;
    int*    tot    = (int*)(ws + off);    off += (size_t)N * 4;
    int*    start  = (int*)(ws + off);    off += (size_t)(N + 1) * 4;
    off = (off + 15) & ~(size_t)15;
    int*    part   = (int*)(ws + off);    off += (size_t)4096 * 4;
    off = (off + 15) & ~(size_t)15;
    int*    sortedJ = (int*)(ws + off);   off += (size_t)P * 4;
    off = (off + 15) & ~(size_t)15;
    int*    invPos  = (int*)(ws + off);   off += (size_t)P * 4;
    off = (off + 63) & ~(size_t)63;
    _Float16* sortedF = (_Float16*)(ws + off); off += (size_t)P * 16 * 2;
    off = (off + 15) & ~(size_t)15;
    __bf16* wf     = (__bf16*)(ws + off); off += (size_t)9 * 4096 * 2;
    // wf matrices: 0=Wi 1=Wj 2=W1_0 3=W2_0 4=W1_1 5=W2_1 6=W1_2 7=W2_2 8=Wv

    const int nRange = (N + NBINR - 1) / NBINR;
    const int nPart = (N + 1023) / 1024;
    const int nTiles = (N + 63) >> 6;
    const int gTiles = (nTiles + 3) / 4;   // 1 tile per wave

    dim3 blk(256);
    k_prep<<<9, blk, 0, stream>>>(Wi, Wj, rW1, rW2, rW1 + 4096, rW2 + 4096,
                                  rW1 + 8192, rW2 + 8192, Wv, wf);
    k_hist2<<<NCHUNK * nRange, blk, 0, stream>>>(pidx, Cmat, P, N, nRange);
    k_scanR<<<(N + 511) / 512, blk, 0, stream>>>(Cmat, tot, N);
    k_scan_a<<<nPart, blk, 0, stream>>>(tot, part, N);
    k_scan_b<<<1, blk, 0, stream>>>(part, nPart);
    k_scan_c<<<nPart, blk, 0, stream>>>(tot, part, start, N, P);
    k_scatter2<<<NCHUNK * nRange, blk, 0, stream>>>(pidx, Cmat, start, sortedJ,
                                                    invPos, P, N, nRange);
    k_gatherF2<<<2048, blk, 0, stream>>>(f_ij, invPos, sortedF, P);
    k_atoms<<<gTiles, blk, 0, stream>>>(emb, wf, bi, bj, v, y16, N);
    k_seg<<<4096, blk, 0, stream>>>(sortedJ, sortedF, start, G, y16, v, N);
    k_post<<<gTiles, blk, 0, stream>>>(wf + (size_t)2 * 4096, rb1, rb2, bv, v, N);
}

// Round 8
// 609.258 us; speedup vs baseline: 1.0515x; 1.0515x over previous
//
#include <hip/hip_runtime.h>
#include <math.h>

#define FDIM 64
#define RDIM 16
#define LN2F 0.69314718055994530942f
#define LTS 68       // LDS tile row stride (floats)
#define NBINR 14336  // bins per range-pass (56KB LDS), 7 ranges cover 100K atoms
#define NCHUNK 64    // pair chunks (Cmat[chunk][bin] aliases workspace region)

typedef __bf16 bf8_t __attribute__((ext_vector_type(8)));
typedef float  f4_t  __attribute__((ext_vector_type(4)));
typedef _Float16 h2_t __attribute__((ext_vector_type(2)));

// Numerically stable softplus (fast intrinsics)
__device__ __forceinline__ float sp(float x) {
    return fmaxf(x, 0.0f) + __logf(1.0f + __expf(-fabsf(x)));
}

// fp16 dot2 with f32 accumulate (V_DOT2_F32_F16); fallback if builtin missing
__device__ __forceinline__ float fdot2f(h2_t a, h2_t b, float c) {
#if __has_builtin(__builtin_amdgcn_fdot2)
    return __builtin_amdgcn_fdot2(a, b, c, false);
#else
    return c + (float)a[0] * (float)b[0] + (float)a[1] * (float)b[1];
#endif
}

// convert one f32 row (16) to fp16 and store 32B
__device__ __forceinline__ void cvt_store16(_Float16* dst, float4 A, float4 B,
                                            float4 C4, float4 D)
{
    h2_t hv[8];
    hv[0] = h2_t{(_Float16)A.x,  (_Float16)A.y};
    hv[1] = h2_t{(_Float16)A.z,  (_Float16)A.w};
    hv[2] = h2_t{(_Float16)B.x,  (_Float16)B.y};
    hv[3] = h2_t{(_Float16)B.z,  (_Float16)B.w};
    hv[4] = h2_t{(_Float16)C4.x, (_Float16)C4.y};
    hv[5] = h2_t{(_Float16)C4.z, (_Float16)C4.w};
    hv[6] = h2_t{(_Float16)D.x,  (_Float16)D.y};
    hv[7] = h2_t{(_Float16)D.z,  (_Float16)D.w};
    *(uint4*)dst       = *(const uint4*)&hv[0];
    *(uint4*)(dst + 8) = *(const uint4*)&hv[4];
}

// ---------------- cvtF: sequential f32 -> f16 stream --------------------------
__global__ __launch_bounds__(256) void k_cvtF(
    const float* __restrict__ f_ij, _Float16* __restrict__ f16, int P)
{
    int t = blockIdx.x * blockDim.x + threadIdx.x;
    int n = gridDim.x * blockDim.x;
    for (int p = t; p < P; p += n) {
        const float4* fp = (const float4*)(f_ij + (size_t)p * RDIM);
        float4 A = fp[0], B = fp[1], C4 = fp[2], D = fp[3];
        cvt_store16(f16 + (size_t)p * RDIM, A, B, C4, D);
    }
}

// ---------------- weight prep: fp32 [k][c] -> bf16 B-fragment layout ----------
__global__ __launch_bounds__(256) void k_prep(
    const float* s0, const float* s1, const float* s2, const float* s3,
    const float* s4, const float* s5, const float* s6, const float* s7,
    const float* s8, __bf16* __restrict__ dst)
{
    const float* srcs[9] = {s0, s1, s2, s3, s4, s5, s6, s7, s8};
    const float* W = srcs[blockIdx.x];
    __bf16* d = dst + (size_t)blockIdx.x * 4096;
    for (int slot = threadIdx.x; slot < 512; slot += 256) {
        int f = slot >> 6, l = slot & 63;
        int kt = f >> 2, nt = f & 3;
        int row0 = kt * 32 + (l >> 4) * 8;
        int col = nt * 16 + (l & 15);
#pragma unroll
        for (int j = 0; j < 8; ++j)
            d[slot * 8 + j] = (__bf16)W[(row0 + j) * FDIM + col];
    }
}

// ---------------- hist: LDS-private per-(chunk,range) histograms --------------
__global__ __launch_bounds__(256) void k_hist2(
    const int* __restrict__ idx_i, int* __restrict__ Cmat,
    int P, int N, int nRange)
{
    __shared__ int h[NBINR];
    const int chunk = blockIdx.x / nRange;
    const int range = blockIdx.x % nRange;
    const int lo = range * NBINR;
    const int nb = min(NBINR, N - lo);
    for (int u = threadIdx.x; u < NBINR; u += 256) h[u] = 0;
    __syncthreads();

    const int chunkSz = (P + NCHUNK - 1) / NCHUNK;
    const int cs = chunk * chunkSz;
    const int ce = min(P, cs + chunkSz);
    int p = cs + threadIdx.x;
    for (; p + 768 < ce; p += 1024) {
        int i0 = idx_i[p];
        int i1 = idx_i[p + 256];
        int i2 = idx_i[p + 512];
        int i3 = idx_i[p + 768];
        unsigned u0 = (unsigned)(i0 - lo);
        unsigned u1 = (unsigned)(i1 - lo);
        unsigned u2 = (unsigned)(i2 - lo);
        unsigned u3 = (unsigned)(i3 - lo);
        if (u0 < (unsigned)nb) atomicAdd(&h[u0], 1);
        if (u1 < (unsigned)nb) atomicAdd(&h[u1], 1);
        if (u2 < (unsigned)nb) atomicAdd(&h[u2], 1);
        if (u3 < (unsigned)nb) atomicAdd(&h[u3], 1);
    }
    for (; p < ce; p += 256) {
        unsigned u = (unsigned)(idx_i[p] - lo);
        if (u < (unsigned)nb) atomicAdd(&h[u], 1);
    }
    __syncthreads();
    for (int u = threadIdx.x; u < nb; u += 256)
        Cmat[(size_t)chunk * N + lo + u] = h[u];
}

// ---------------- scanR: Cmat -> per-chunk exclusive bases (in place) + totals
__global__ __launch_bounds__(256) void k_scanR(
    int* __restrict__ Cmat, int* __restrict__ tot, int N)
{
    const int bA = blockIdx.x * 512 + threadIdx.x;
    const int bB = bA + 256;
    const bool okA = bA < N, okB = bB < N;
    int runA = 0, runB = 0;
    for (int c = 0; c < NCHUNK; ++c) {
        const size_t base = (size_t)c * N;
        if (okA) { int val = Cmat[base + bA]; Cmat[base + bA] = runA; runA += val; }
        if (okB) { int val = Cmat[base + bB]; Cmat[base + bB] = runB; runB += val; }
    }
    if (okA) tot[bA] = runA;
    if (okB) tot[bB] = runB;
}

// ---------------- tile in: coalesced global -> wave-private LDS ----------------
__device__ __forceinline__ void tile_in(float* T, const float* __restrict__ src,
                                        int a0, int rows, int lane)
{
#pragma unroll 4
    for (int i = 0; i < 16; ++i) {
        int r = i * 4 + (lane >> 4);
        int col = (lane & 15) * 4;
        float4 val = make_float4(0.f, 0.f, 0.f, 0.f);
        if (r < rows) val = *(const float4*)&src[(size_t)(a0 + r) * FDIM + col];
        *(float4*)&T[r * LTS + col] = val;
    }
}

// build A-fragments (bf16) for a 64x64 LDS tile: aF[mt][kt]
__device__ __forceinline__ void build_a(const float* T, int lane, bool actLn2,
                                        bf8_t (&aF)[4][2])
{
    const int l15 = lane & 15, quad = lane >> 4;
#pragma unroll
    for (int mt = 0; mt < 4; ++mt) {
#pragma unroll
        for (int kt = 0; kt < 2; ++kt) {
            const float* rp = &T[(mt * 16 + l15) * LTS + kt * 32 + quad * 8];
            float4 u0 = *(const float4*)rp;
            float4 u1 = *(const float4*)(rp + 4);
            float e[8] = {u0.x, u0.y, u0.z, u0.w, u1.x, u1.y, u1.z, u1.w};
            bf8_t f;
#pragma unroll
            for (int j = 0; j < 8; ++j) {
                float t = actLn2 ? (sp(e[j]) - LN2F) : e[j];
                f[j] = (__bf16)t;
            }
            aF[mt][kt] = f;
        }
    }
}

// ---------------- k_atoms: x=sp(emb)-ln2; v=sp(x@Wi+bi); y16=sp(x@Wj+bj) ------
__global__ __launch_bounds__(256) void k_atoms(
    const float* __restrict__ emb, const __bf16* __restrict__ wf,
    const float* __restrict__ bi, const float* __restrict__ bj,
    float* __restrict__ v, _Float16* __restrict__ y16, int N)
{
    __shared__ float tile[4][64 * LTS];
    const int lane = threadIdx.x & 63;
    const int wv = threadIdx.x >> 6;
    float* T = tile[wv];
    const int l15 = lane & 15, quad = lane >> 4;

    const bf8_t* wiF = (const bf8_t*)wf;            // matrix 0
    const bf8_t* wjF = (const bf8_t*)(wf + 4096);   // matrix 1
    bf8_t wi[2][4], wj[2][4];
#pragma unroll
    for (int kt = 0; kt < 2; ++kt)
#pragma unroll
        for (int nt = 0; nt < 4; ++nt) {
            wi[kt][nt] = wiF[(kt * 4 + nt) * 64 + lane];
            wj[kt][nt] = wjF[(kt * 4 + nt) * 64 + lane];
        }
    float biv[4], bjv[4];
#pragma unroll
    for (int nt = 0; nt < 4; ++nt) {
        biv[nt] = bi[nt * 16 + l15];
        bjv[nt] = bj[nt * 16 + l15];
    }

    const int nTiles = (N + 63) >> 6;
    for (int t = blockIdx.x * 4 + wv; t < nTiles; t += gridDim.x * 4) {
        const int a0 = t << 6;
        const int rows = min(64, N - a0);
        tile_in(T, emb, a0, rows, lane);
        bf8_t aF[4][2];
        build_a(T, lane, true, aF);
#pragma unroll
        for (int mt = 0; mt < 4; ++mt)
#pragma unroll
            for (int nt = 0; nt < 4; ++nt) {
                f4_t acc = {biv[nt], biv[nt], biv[nt], biv[nt]};
                acc = __builtin_amdgcn_mfma_f32_16x16x32_bf16(aF[mt][0], wi[0][nt], acc, 0, 0, 0);
                acc = __builtin_amdgcn_mfma_f32_16x16x32_bf16(aF[mt][1], wi[1][nt], acc, 0, 0, 0);
#pragma unroll
                for (int reg = 0; reg < 4; ++reg) {
                    int r = mt * 16 + quad * 4 + reg;
                    if (r < rows) v[(size_t)(a0 + r) * FDIM + nt * 16 + l15] = sp(acc[reg]);
                }
            }
#pragma unroll
        for (int mt = 0; mt < 4; ++mt)
#pragma unroll
            for (int nt = 0; nt < 4; ++nt) {
                f4_t acc = {bjv[nt], bjv[nt], bjv[nt], bjv[nt]};
                acc = __builtin_amdgcn_mfma_f32_16x16x32_bf16(aF[mt][0], wj[0][nt], acc, 0, 0, 0);
                acc = __builtin_amdgcn_mfma_f32_16x16x32_bf16(aF[mt][1], wj[1][nt], acc, 0, 0, 0);
#pragma unroll
                for (int reg = 0; reg < 4; ++reg) {
                    int r = mt * 16 + quad * 4 + reg;
                    if (r < rows)
                        y16[(size_t)(a0 + r) * FDIM + nt * 16 + l15] = (_Float16)sp(acc[reg]);
                }
            }
    }
}

// ---------------- k_post: fused 3 residual blocks + final projection (MFMA) ---
__global__ __launch_bounds__(256) void k_post(
    const __bf16* __restrict__ wf,
    const float* __restrict__ rb1, const float* __restrict__ rb2,
    const float* __restrict__ bv,
    float* __restrict__ v, int N)
{
    __shared__ float tile[4][64 * LTS];
    const int lane = threadIdx.x & 63;
    const int wv = threadIdx.x >> 6;
    float* T = tile[wv];
    const int l15 = lane & 15, quad = lane >> 4;

    float b1v[3][4], b2v[3][4], bvv[4];
#pragma unroll
    for (int l = 0; l < 3; ++l)
#pragma unroll
        for (int nt = 0; nt < 4; ++nt) {
            b1v[l][nt] = rb1[l * FDIM + nt * 16 + l15];
            b2v[l][nt] = rb2[l * FDIM + nt * 16 + l15];
        }
#pragma unroll
    for (int nt = 0; nt < 4; ++nt) bvv[nt] = bv[nt * 16 + l15];

    const int nTiles = (N + 63) >> 6;
    for (int t = blockIdx.x * 4 + wv; t < nTiles; t += gridDim.x * 4) {
        const int a0 = t << 6;
        const int rows = min(64, N - a0);
        tile_in(T, v, a0, rows, lane);
        float vC[16][4];
#pragma unroll
        for (int mt = 0; mt < 4; ++mt)
#pragma unroll
            for (int nt = 0; nt < 4; ++nt)
#pragma unroll
                for (int reg = 0; reg < 4; ++reg)
                    vC[mt * 4 + nt][reg] =
                        T[(mt * 16 + quad * 4 + reg) * LTS + nt * 16 + l15];

        for (int l = 0; l < 3; ++l) {
            const bf8_t* w1f = (const bf8_t*)(wf + (size_t)(2 * l) * 4096);
            const bf8_t* w2f = (const bf8_t*)(wf + (size_t)(2 * l + 1) * 4096);
            bf8_t aF[4][2];
            build_a(T, lane, false, aF);
#pragma unroll
            for (int mt = 0; mt < 4; ++mt)
#pragma unroll
                for (int nt = 0; nt < 4; ++nt) {
                    f4_t acc = {b1v[l][nt], b1v[l][nt], b1v[l][nt], b1v[l][nt]};
                    acc = __builtin_amdgcn_mfma_f32_16x16x32_bf16(aF[mt][0], w1f[(0 * 4 + nt) * 64 + lane], acc, 0, 0, 0);
                    acc = __builtin_amdgcn_mfma_f32_16x16x32_bf16(aF[mt][1], w1f[(1 * 4 + nt) * 64 + lane], acc, 0, 0, 0);
#pragma unroll
                    for (int reg = 0; reg < 4; ++reg)
                        T[(mt * 16 + quad * 4 + reg) * LTS + nt * 16 + l15] = sp(acc[reg]);
                }
            bf8_t hF[4][2];
            build_a(T, lane, false, hF);
#pragma unroll
            for (int mt = 0; mt < 4; ++mt)
#pragma unroll
                for (int nt = 0; nt < 4; ++nt) {
                    f4_t acc = {b2v[l][nt], b2v[l][nt], b2v[l][nt], b2v[l][nt]};
                    acc = __builtin_amdgcn_mfma_f32_16x16x32_bf16(hF[mt][0], w2f[(0 * 4 + nt) * 64 + lane], acc, 0, 0, 0);
                    acc = __builtin_amdgcn_mfma_f32_16x16x32_bf16(hF[mt][1], w2f[(1 * 4 + nt) * 64 + lane], acc, 0, 0, 0);
#pragma unroll
                    for (int reg = 0; reg < 4; ++reg)
                        vC[mt * 4 + nt][reg] += acc[reg];
                }
            if (l < 2) {
#pragma unroll
                for (int mt = 0; mt < 4; ++mt)
#pragma unroll
                    for (int nt = 0; nt < 4; ++nt)
#pragma unroll
                        for (int reg = 0; reg < 4; ++reg)
                            T[(mt * 16 + quad * 4 + reg) * LTS + nt * 16 + l15] =
                                vC[mt * 4 + nt][reg];
            }
        }
#pragma unroll
        for (int mt = 0; mt < 4; ++mt)
#pragma unroll
            for (int nt = 0; nt < 4; ++nt)
#pragma unroll
                for (int reg = 0; reg < 4; ++reg)
                    T[(mt * 16 + quad * 4 + reg) * LTS + nt * 16 + l15] =
                        sp(vC[mt * 4 + nt][reg]);
        bf8_t fF[4][2];
        build_a(T, lane, false, fF);
        const bf8_t* wvf = (const bf8_t*)(wf + (size_t)6 * 4096);
#pragma unroll
        for (int mt = 0; mt < 4; ++mt)
#pragma unroll
            for (int nt = 0; nt < 4; ++nt) {
                f4_t acc = {bvv[nt], bvv[nt], bvv[nt], bvv[nt]};
                acc = __builtin_amdgcn_mfma_f32_16x16x32_bf16(fF[mt][0], wvf[(0 * 4 + nt) * 64 + lane], acc, 0, 0, 0);
                acc = __builtin_amdgcn_mfma_f32_16x16x32_bf16(fF[mt][1], wvf[(1 * 4 + nt) * 64 + lane], acc, 0, 0, 0);
#pragma unroll
                for (int reg = 0; reg < 4; ++reg) {
                    int r = mt * 16 + quad * 4 + reg;
                    if (r < rows) v[(size_t)(a0 + r) * FDIM + nt * 16 + l15] = acc[reg];
                }
            }
    }
}

// ---------------- global scan over per-bin totals -----------------------------
__global__ __launch_bounds__(256) void k_scan_a(
    const int* __restrict__ cnt, int* __restrict__ part, int N)
{
    __shared__ int red[256];
    int b = blockIdx.x, t = threadIdx.x;
    int base = b * 1024 + t * 4;
    int s = 0;
#pragma unroll
    for (int i = 0; i < 4; ++i) { int a = base + i; if (a < N) s += cnt[a]; }
    red[t] = s; __syncthreads();
    for (int off = 128; off > 0; off >>= 1) {
        if (t < off) red[t] += red[t + off];
        __syncthreads();
    }
    if (t == 0) part[b] = red[0];
}

__global__ __launch_bounds__(256) void k_scan_b(int* __restrict__ part, int nPart)
{
    __shared__ int lds[256];
    int t = threadIdx.x;
    int base = t * 4;
    int v[4]; int s = 0;
#pragma unroll
    for (int i = 0; i < 4; ++i) { v[i] = (base + i < nPart) ? part[base + i] : 0; s += v[i]; }
    lds[t] = s; __syncthreads();
    int run = s;
    for (int off = 1; off < 256; off <<= 1) {
        int x = (t >= off) ? lds[t - off] : 0;
        __syncthreads();
        lds[t] += x;
        __syncthreads();
    }
    int excl = lds[t] - run;
#pragma unroll
    for (int i = 0; i < 4; ++i) { if (base + i < nPart) { part[base + i] = excl; excl += v[i]; } }
}

__global__ __launch_bounds__(256) void k_scan_c(
    const int* __restrict__ cnt, const int* __restrict__ part,
    int* __restrict__ start, int N, int P)
{
    __shared__ int lds[256];
    int b = blockIdx.x, t = threadIdx.x;
    int base = b * 1024 + t * 4;
    int v[4]; int s = 0;
#pragma unroll
    for (int i = 0; i < 4; ++i) { int a = base + i; v[i] = (a < N) ? cnt[a] : 0; s += v[i]; }
    lds[t] = s; __syncthreads();
    int run = s;
    for (int off = 1; off < 256; off <<= 1) {
        int x = (t >= off) ? lds[t - off] : 0;
        __syncthreads();
        lds[t] += x;
        __syncthreads();
    }
    int pre = part[b] + (lds[t] - run);
#pragma unroll
    for (int i = 0; i < 4; ++i) {
        int a = base + i;
        if (a < N) { start[a] = pre; pre += v[i]; }
    }
    if (b == 0 && t == 0) start[N] = P;
}

// ---------------- scatter: LDS cursors, LDS atomic returns (R4 form) ----------
__global__ __launch_bounds__(256) void k_scatter2(
    const int* __restrict__ pidx, const int* __restrict__ Cmat,
    const int* __restrict__ start, int2* __restrict__ sorted,
    int P, int N, int nRange)
{
    __shared__ int cur[NBINR];
    const int chunk = blockIdx.x / nRange;
    const int range = blockIdx.x % nRange;
    const int lo = range * NBINR;
    const int nb = min(NBINR, N - lo);
    for (int u = threadIdx.x; u < nb; u += 256)
        cur[u] = start[lo + u] + Cmat[(size_t)chunk * N + lo + u];
    __syncthreads();

    const int chunkSz = (P + NCHUNK - 1) / NCHUNK;
    const int cs = chunk * chunkSz;
    const int ce = min(P, cs + chunkSz);
    int p = cs + threadIdx.x;
    for (; p + 768 < ce; p += 1024) {
        int i0 = pidx[p];
        int i1 = pidx[p + 256];
        int i2 = pidx[p + 512];
        int i3 = pidx[p + 768];
        int j0 = pidx[P + p];
        int j1 = pidx[P + p + 256];
        int j2 = pidx[P + p + 512];
        int j3 = pidx[P + p + 768];
        unsigned u0 = (unsigned)(i0 - lo);
        unsigned u1 = (unsigned)(i1 - lo);
        unsigned u2 = (unsigned)(i2 - lo);
        unsigned u3 = (unsigned)(i3 - lo);
        if (u0 < (unsigned)nb) { int pos = atomicAdd(&cur[u0], 1); sorted[pos] = make_int2(p, j0); }
        if (u1 < (unsigned)nb) { int pos = atomicAdd(&cur[u1], 1); sorted[pos] = make_int2(p + 256, j1); }
        if (u2 < (unsigned)nb) { int pos = atomicAdd(&cur[u2], 1); sorted[pos] = make_int2(p + 512, j2); }
        if (u3 < (unsigned)nb) { int pos = atomicAdd(&cur[u3], 1); sorted[pos] = make_int2(p + 768, j3); }
    }
    for (; p < ce; p += 256) {
        int i = pidx[p];
        unsigned u = (unsigned)(i - lo);
        if (u < (unsigned)nb) {
            int j = pidx[P + p];
            int pos = atomicAdd(&cur[u], 1);
            sorted[pos] = make_int2(p, j);
        }
    }
}

// ---------------- k_seg -------------------------------------------------------
// out[a,c] = sum_p dot16(G[c,:], f16[p,:]) * y16[j_p, c]
// sorted (p,j) read coalesced once per 64-block; p,j via readlane (uniform).
// f16 rows: wave-uniform 32B SCALAR loads (SGPR-resident, zero VGPR cost);
// table is 64MB -> L3-resident, line waste absorbed on re-touch.
// y16 rows: 128B = one line per gather, table 12.8MB L3-resident.
__global__ __launch_bounds__(256) void k_seg(
    const int2* __restrict__ sorted, const _Float16* __restrict__ f16,
    const int* __restrict__ start, const float* __restrict__ G,
    const _Float16* __restrict__ y16, float* __restrict__ v, int N)
{
    const int c = threadIdx.x & 63;
    const int w = __builtin_amdgcn_readfirstlane((blockIdx.x << 2) | (threadIdx.x >> 6));
    const int nw = gridDim.x << 2;

    // G row for this lane, packed to fp16 pairs (8 dot2 operands)
    h2_t g2[8];
    {
        const float4* gp = (const float4*)(G + c * RDIM);
        float4 g0 = gp[0], g1 = gp[1], g2v = gp[2], g3 = gp[3];
        g2[0] = h2_t{(_Float16)g0.x, (_Float16)g0.y};
        g2[1] = h2_t{(_Float16)g0.z, (_Float16)g0.w};
        g2[2] = h2_t{(_Float16)g1.x, (_Float16)g1.y};
        g2[3] = h2_t{(_Float16)g1.z, (_Float16)g1.w};
        g2[4] = h2_t{(_Float16)g2v.x, (_Float16)g2v.y};
        g2[5] = h2_t{(_Float16)g2v.z, (_Float16)g2v.w};
        g2[6] = h2_t{(_Float16)g3.x, (_Float16)g3.y};
        g2[7] = h2_t{(_Float16)g3.z, (_Float16)g3.w};
    }

    for (int a = w; a < N; a += nw) {
        const int s = __builtin_amdgcn_readfirstlane(start[a]);
        const int e = __builtin_amdgcn_readfirstlane(start[a + 1]);
        float vold = v[(size_t)a * FDIM + c];   // hoist RMW read over the pair loop
        float acc0 = 0.f, acc1 = 0.f, acc2 = 0.f, acc3 = 0.f;

        for (int base = s; base < e; base += 64) {
            const int nn = (e - base < 64) ? (e - base) : 64;
            const int li = (c < nn) ? c : (nn - 1);
            const int2 E = sorted[base + li];   // lane l holds (p,j) of pair base+l
            const int pk = E.x, jk = E.y;

            int k = 0;
            for (; k + 8 <= nn; k += 8) {
                int pp[8], jj[8];
#pragma unroll
                for (int u = 0; u < 8; ++u) {
                    pp[u] = __builtin_amdgcn_readlane(pk, k + u);
                    jj[u] = __builtin_amdgcn_readlane(jk, k + u);
                }
                // issue all independent gathers (vector y + uniform/scalar f rows)
                float yv[8];
#pragma unroll
                for (int u = 0; u < 8; ++u)
                    yv[u] = (float)y16[(size_t)jj[u] * FDIM + c];
#pragma unroll
                for (int u = 0; u < 8; ++u) {
                    const h2_t* fr = (const h2_t*)(f16 + (size_t)pp[u] * RDIM);
                    float d = 0.f;
#pragma unroll
                    for (int r = 0; r < 8; ++r)
                        d = fdot2f(fr[r], g2[r], d);
                    if ((u & 3) == 0) acc0 = fmaf(d, yv[u], acc0);
                    else if ((u & 3) == 1) acc1 = fmaf(d, yv[u], acc1);
                    else if ((u & 3) == 2) acc2 = fmaf(d, yv[u], acc2);
                    else acc3 = fmaf(d, yv[u], acc3);
                }
            }
            for (; k < nn; ++k) {
                const int p0 = __builtin_amdgcn_readlane(pk, k);
                const int j0 = __builtin_amdgcn_readlane(jk, k);
                float y0 = (float)y16[(size_t)j0 * FDIM + c];
                const h2_t* fr = (const h2_t*)(f16 + (size_t)p0 * RDIM);
                float d = 0.f;
#pragma unroll
                for (int r = 0; r < 8; ++r)
                    d = fdot2f(fr[r], g2[r], d);
                acc0 = fmaf(d, y0, acc0);
            }
        }

        v[(size_t)a * FDIM + c] = vold + (acc0 + acc1) + (acc2 + acc3);
    }
}

extern "C" void kernel_launch(void* const* d_in, const int* in_sizes, int n_in,
                              void* d_out, int out_size, void* d_ws, size_t ws_size,
                              hipStream_t stream)
{
    const int*   pidx = (const int*)d_in[0];    // [2, P]
    const float* f_ij = (const float*)d_in[1];  // [P, 1, R]
    const float* emb  = (const float*)d_in[3];  // [N, F]
    const float* G    = (const float*)d_in[4];  // [F, R]
    const float* Wi   = (const float*)d_in[5];
    const float* bi   = (const float*)d_in[6];
    const float* Wj   = (const float*)d_in[7];
    const float* bj   = (const float*)d_in[8];
    const float* rW1  = (const float*)d_in[9];
    const float* rb1  = (const float*)d_in[10];
    const float* rW2  = (const float*)d_in[11];
    const float* rb2  = (const float*)d_in[12];
    const float* Wv   = (const float*)d_in[13];
    const float* bv   = (const float*)d_in[14];

    const int P = in_sizes[0] / 2;
    const int N = in_sizes[3] / FDIM;

    float* v = (float*)d_out;

    // workspace layout. Cmat (int[NCHUNK*N] = 25.6MB) shares its region with
    // y16 (N*64 fp16 = 12.8MB): Cmat is dead after k_scatter2; k_atoms writes
    // y16 afterwards.
    char* ws = (char*)d_ws;
    size_t off = 0;
    _Float16* y16  = (_Float16*)(ws + off);
    int*    Cmat   = (int*)(ws + off);    off += (size_t)N * FDIM * 4;
    int*    tot    = (int*)(ws + off);    off += (size_t)N * 4;
    int*    start  = (int*)(ws + off);    off += (size_t)(N + 1) * 4;
    off = (off + 15) & ~(size_t)15;
    int*    part   = (int*)(ws + off);    off += (size_t)4096 * 4;
    off = (off + 15) & ~(size_t)15;
    int2*   sorted = (int2*)(ws + off);   off += (size_t)P * 8;
    off = (off + 63) & ~(size_t)63;
    _Float16* f16  = (_Float16*)(ws + off); off += (size_t)P * RDIM * 2;
    off = (off + 15) & ~(size_t)15;
    __bf16* wf     = (__bf16*)(ws + off); off += (size_t)9 * 4096 * 2;
    // wf matrices: 0=Wi 1=Wj 2=W1_0 3=W2_0 4=W1_1 5=W2_1 6=W1_2 7=W2_2 8=Wv

    const int nRange = (N + NBINR - 1) / NBINR;
    const int nPart = (N + 1023) / 1024;
    const int nTiles = (N + 63) >> 6;
    const int gTiles = (nTiles + 3) / 4;   // 1 tile per wave

    dim3 blk(256);
    k_prep<<<9, blk, 0, stream>>>(Wi, Wj, rW1, rW2, rW1 + 4096, rW2 + 4096,
                                  rW1 + 8192, rW2 + 8192, Wv, wf);
    k_cvtF<<<2048, blk, 0, stream>>>(f_ij, f16, P);
    k_hist2<<<NCHUNK * nRange, blk, 0, stream>>>(pidx, Cmat, P, N, nRange);
    k_scanR<<<(N + 511) / 512, blk, 0, stream>>>(Cmat, tot, N);
    k_scan_a<<<nPart, blk, 0, stream>>>(tot, part, N);
    k_scan_b<<<1, blk, 0, stream>>>(part, nPart);
    k_scan_c<<<nPart, blk, 0, stream>>>(tot, part, start, N, P);
    k_scatter2<<<NCHUNK * nRange, blk, 0, stream>>>(pidx, Cmat, start, sorted, P, N, nRange);
    k_atoms<<<gTiles, blk, 0, stream>>>(emb, wf, bi, bj, v, y16, N);
    k_seg<<<4096, blk, 0, stream>>>(sorted, f16, start, G, y16, v, N);
    k_post<<<gTiles, blk, 0, stream>>>(wf + (size_t)2 * 4096, rb1, rb2, bv, v, N);
}